// Round 7
// baseline (340.874 us; speedup 1.0000x reference)
//
#include <hip/hip_runtime.h>

// Problem constants (fixed by the reference):
#define E_ENV  8192
#define A_AG   128
#define K_PASS 512
#define ROW_F  11
#define SLICE_F  (K_PASS * ROW_F)   // 5632 floats per env slice
#define SLICE_V4 (SLICE_F / 4)      // 1408 float4 per env slice
#define ITERS    (SLICE_V4 / A_AG)  // 11 float4s per thread
#define GRID_B   1024
#define NE       (E_ENV / GRID_B)   // 8 envs per block

// ---------------------------------------------------------------------------
// Persistent double-buffered pipeline (T3+T4): 1024 blocks x 128 threads,
// each block processes 8 consecutive envs. ALL global reads (slice AND
// resolve inputs) are staged via global_load_lds; the loop body contains no
// other vector-memory ops, so the per-wave vmcnt ledger is exact:
//   per env: 15 gload_lds (11 slice + vec + tgt + acc + pick), 11 stores.
//   j==0     : out = [ts prologue] + 15(e0) + 15(e1)      -> wait vmcnt(15)
//   0<j<NE-1 : out = 15(j) + 11 st(j-1) + 15(j+1) = 41    -> wait vmcnt(26)
//   j==NE-1  : out = 15(j) + 11 st(j-1)           = 26    -> wait vmcnt(11)
// vmcnt completes oldest-first, so each wait proves "stage(j) arrived"
// while keeping stage(j+1) and the previous stores IN FLIGHT (never 0 in
// the loop). Intermediate barriers are lgkmcnt-only. Result: continuous
// ~26 KB read + 22.5 KB write in flight per block instead of r6's one-shot
// burst chain (r6: ~105 us = 2.8 TB/s; floor for 292 MB is ~46 us).
//
// LDS: 2*22528 + 2*2048 + 3*2*512 + 2048 + 24 = 54296 B -> 2 blocks/CU.
// Timesteps are loaded in the PROLOGUE (before any staging) so even if
// emitted as vector loads they occupy the oldest slots and drain first --
// the ledger stays correct for any merge the compiler picks.
// ---------------------------------------------------------------------------

typedef const __attribute__((address_space(1))) void* gp_t;
typedef __attribute__((address_space(3))) void*       lp_t;

// LDS-only barrier: orders ds ops across the block WITHOUT draining vmcnt.
__device__ __forceinline__ void bar_lds()
{
    asm volatile("s_waitcnt lgkmcnt(0)" ::: "memory");
    __builtin_amdgcn_s_barrier();
    asm volatile("" ::: "memory");
}

__global__ __launch_bounds__(128) void k_fused(
    const float4* __restrict__ pass4,
    const int*    __restrict__ accepts,
    const int*    __restrict__ picks,
    const int*    __restrict__ targets,
    const float4* __restrict__ vectors,
    const int*    __restrict__ timesteps,
    float4*       __restrict__ out4)
{
    __shared__ float4 slice[2][SLICE_V4];   // 2 x 22528 B
    __shared__ float4 vbuf[2][A_AG];        // staged vectors
    __shared__ int    tbuf[2][A_AG];        // staged targets
    __shared__ int    abuf[2][A_AG];        // staged accepts
    __shared__ int    pbuf[2][A_AG];        // staged picks
    __shared__ int    cnt[K_PASS];          // dup counter per local passenger
    __shared__ float  swv[2];
    __shared__ int    swi[2];

    const int a  = threadIdx.x;             // agent 0..127
    const int e0 = blockIdx.x * NE;

    // ---- prologue: timesteps for all NE envs, BEFORE any staging ----
    float tsf[NE];
    #pragma unroll
    for (int j = 0; j < NE; ++j)
        tsf[j] = (float)timesteps[e0 + j];

    auto STAGE = [&](int env, int bi) {
        const float4* s4 = pass4 + (size_t)env * SLICE_V4;
        #pragma unroll
        for (int it = 0; it < ITERS; ++it) {
            const int idx = a + it * A_AG;
            __builtin_amdgcn_global_load_lds((gp_t)(s4 + idx),
                                             (lp_t)(&slice[bi][idx]), 16, 0, 0);
        }
        __builtin_amdgcn_global_load_lds((gp_t)(vectors + (size_t)env * A_AG + a),
                                         (lp_t)(&vbuf[bi][a]), 16, 0, 0);
        __builtin_amdgcn_global_load_lds((gp_t)(targets + env * A_AG + a),
                                         (lp_t)(&tbuf[bi][a]), 4, 0, 0);
        __builtin_amdgcn_global_load_lds((gp_t)(accepts + env * A_AG + a),
                                         (lp_t)(&abuf[bi][a]), 4, 0, 0);
        __builtin_amdgcn_global_load_lds((gp_t)(picks + env * A_AG + a),
                                         (lp_t)(&pbuf[bi][a]), 4, 0, 0);
    };

    STAGE(e0, 0);

    #pragma unroll
    for (int j = 0; j < NE; ++j) {
        const int cur = j & 1;
        const int e   = e0 + j;

        // issue next env's staging into the other buffer (stays in flight
        // across everything below)
        if (j + 1 < NE) STAGE(e + 1, cur ^ 1);

        // counted wait: prove stage(j) arrived, keep the rest in flight
        if (j == 0)          asm volatile("s_waitcnt vmcnt(15)" ::: "memory");
        else if (j + 1 < NE) asm volatile("s_waitcnt vmcnt(26)" ::: "memory");
        else                 asm volatile("s_waitcnt vmcnt(11)" ::: "memory");
        __builtin_amdgcn_s_barrier();
        asm volatile("" ::: "memory");

        // ---- resolve inputs from LDS ----
        float4 v  = vbuf[cur][a];
        int   t   = tbuf[cur][a];
        int   acc = abuf[cur][a];
        int   pk  = pbuf[cur][a];

        bool invalid = (v.x == -100.0f) && (v.y == -100.0f) &&
                       (v.z == -100.0f) && (v.w == -100.0f);
        float dx = v.x - v.z, dy = v.y - v.w;
        float d = sqrtf(dx * dx + dy * dy);
        if (invalid) d = INFINITY;

        const int tl = t - e * K_PASS;      // local 0..511
        int at = (acc != 0) ? t : -100;

        #pragma unroll
        for (int jj = 0; jj < K_PASS / A_AG; ++jj)
            cnt[a + jj * A_AG] = 0;
        bar_lds();

        if (at >= 0) atomicAdd(&cnt[tl], 1);
        bar_lds();

        // single iteration of the reference while_loop (one pass kills all
        // dups: only the env-wide argmin among dup agents survives)
        bool dup = (at >= 0) && (cnt[tl] > 1);
        float bv = dup ? d : INFINITY;
        int   bi = a;
        #pragma unroll
        for (int off = 32; off > 0; off >>= 1) {   // wave-64 butterfly argmin
            float ov = __shfl_xor(bv, off);
            int   oi = __shfl_xor(bi, off);
            if (ov < bv || (ov == bv && oi < bi)) { bv = ov; bi = oi; }
        }
        int wave = a >> 6;
        if ((a & 63) == 0) { swv[wave] = bv; swi[wave] = bi; }
        bar_lds();
        float v0 = swv[0], v1 = swv[1];
        int   i0 = swi[0], i1 = swi[1];
        // tie -> smaller index (wave 0) wins: matches jnp.argmin first-index
        int bidx = (v1 < v0 || (v1 == v0 && i1 < i0)) ? i1 : i0;

        int f = (dup && a != bidx) ? -100 : at;

        // ---- patch staged slice in LDS ----
        float* sf = (float*)&slice[cur][0];
        // accept: at most one surviving agent per passenger -> no race
        if (f >= 0) {
            sf[tl * ROW_F + 6] = 1.0f;
            sf[tl * ROW_F + 7] = (float)a;
            sf[tl * ROW_F + 9] = tsf[j];
        }
        bar_lds();
        // pick override (col6=2.0 overwrites accept; same-value writers benign)
        if ((pk != 0) && d < 1e-6f) {
            sf[tl * ROW_F + 6]  = 2.0f;
            sf[tl * ROW_F + 10] = tsf[j];
        }
        bar_lds();

        // ---- stream patched slice -> global (stores stay in flight) ----
        float4* dst = out4 + (size_t)e * SLICE_V4;
        #pragma unroll
        for (int it = 0; it < ITERS; ++it) {
            const int idx = a + it * A_AG;
            dst[idx] = slice[cur][idx];
        }

        // bottom barrier: this buffer gets re-staged next iteration; ensure
        // every wave's ds_reads of it are complete (lgkm only -- the new
        // gload_lds data returns hundreds of cycles after issue)
        bar_lds();
    }
}

// ---------------------------------------------------------------------------
extern "C" void kernel_launch(void* const* d_in, const int* in_sizes, int n_in,
                              void* d_out, int out_size, void* d_ws, size_t ws_size,
                              hipStream_t stream)
{
    const float* passengers = (const float*)d_in[0];
    const int*   accepts    = (const int*)d_in[1];
    const int*   picks      = (const int*)d_in[2];
    const int*   targets    = (const int*)d_in[3];
    const float* vectors    = (const float*)d_in[4];
    const int*   timesteps  = (const int*)d_in[5];
    float*       out        = (float*)d_out;

    k_fused<<<GRID_B, A_AG, 0, stream>>>(
        (const float4*)passengers, accepts, picks, targets,
        (const float4*)vectors, timesteps, (float4*)out);
}